// Round 2
// baseline (316.449 us; speedup 1.0000x reference)
//
#include <hip/hip_runtime.h>
#include <math.h>

#define T_OBS 256
#define NY 128
#define NITER 150

// ---- gfx9/CDNA DPP wave64 reduction: row_shr 1,2,4,8 + bcast15 + bcast31 ----
#define DPP_ROW_SHR1 0x111
#define DPP_ROW_SHR2 0x112
#define DPP_ROW_SHR4 0x114
#define DPP_ROW_SHR8 0x118
#define DPP_BCAST15  0x142
#define DPP_BCAST31  0x143

#define DPP_ADD_F32(x, ctrl) \
    (x) += __int_as_float(__builtin_amdgcn_update_dpp(0, __float_as_int(x), (ctrl), 0xf, 0xf, true))

// Interleaved dual wave-sum; returns uniform totals in a,b.
__device__ __forceinline__ void wave_sum2(float& a, float& b) {
    DPP_ADD_F32(a, DPP_ROW_SHR1); DPP_ADD_F32(b, DPP_ROW_SHR1);
    DPP_ADD_F32(a, DPP_ROW_SHR2); DPP_ADD_F32(b, DPP_ROW_SHR2);
    DPP_ADD_F32(a, DPP_ROW_SHR4); DPP_ADD_F32(b, DPP_ROW_SHR4);
    DPP_ADD_F32(a, DPP_ROW_SHR8); DPP_ADD_F32(b, DPP_ROW_SHR8);
    DPP_ADD_F32(a, DPP_BCAST15);  DPP_ADD_F32(b, DPP_BCAST15);
    DPP_ADD_F32(a, DPP_BCAST31);  DPP_ADD_F32(b, DPP_BCAST31);
    a = __int_as_float(__builtin_amdgcn_readlane(__float_as_int(a), 63));
    b = __int_as_float(__builtin_amdgcn_readlane(__float_as_int(b), 63));
}

__device__ __forceinline__ float rl(float x, int l) {
    return __int_as_float(__builtin_amdgcn_readlane(__float_as_int(x), l));
}

// ---------------- kernel 1: Y_hat = X @ W^T + b ; ep = Y - Y_hat ----------------
__global__ __launch_bounds__(128)
void pred_kernel(const float* __restrict__ X, const float* __restrict__ Y,
                 const float* __restrict__ W, const float* __restrict__ b,
                 float* __restrict__ yhat, float* __restrict__ ep) {
    __shared__ float xrow[64];
    const int t = blockIdx.x;
    const int j = threadIdx.x;
    if (j < 64) xrow[j] = X[t * 64 + j];
    __syncthreads();
    const float* wr = W + j * 64;
    float acc = 0.f;
#pragma unroll
    for (int x = 0; x < 64; ++x) acc = fmaf(xrow[x], wr[x], acc);
    const float yh = acc + b[j];
    yhat[t * NY + j] = yh;
    ep[t * NY + j] = Y[t * NY + j] - yh;
}

// ---------------- kernel 2: one DRO solve per block, 512 threads (8 waves) ----------------
// 2 waves/SIMD of TLP: two waves' serial DPP/readlane/Michelot chains interleave.
// Phase A: thread (t = tid&255, h = tid>>8) computes half-dot over cols [64h,64h+64).
// Phase B: wave wid owns rows [32*wid, 32*wid+32), lane owns cols {2*lane, 2*lane+1}.
__global__ __launch_bounds__(512, 2)
void dro_kernel(const float* __restrict__ ep_g, const float* __restrict__ yhat_g,
                float* __restrict__ z_out,
                const float* __restrict__ d_delta, const float* __restrict__ d_gamma) {
    __shared__ __align__(16) float part_lds[T_OBS * 2];   // [row][half] phase-A partials
    __shared__ __align__(16) float gz_f[8 * 130];         // [wave][col(+pad 130)] phase-B partials
    __shared__ __align__(16) float red_s[16];             // per-wave {S1,S2}

    const int tid  = threadIdx.x;
    const int lane = tid & 63;
    const int wid  = tid >> 6;
    const int blk  = blockIdx.x;
    const int h    = tid >> 8;          // phase-A column half (uniform per wave)
    const int trow = tid & 255;         // phase-A row
    const int m    = lane & 31;
    const int prow = wid * 32 + m;      // phase-B / reduction row (2 lanes per row)
    const int j0   = lane << 1;         // this lane's column pair

    // rA: ep[trow][64h .. 64h+63]  (16 float4 = 64 VGPRs)
    float4 rA[16];
    {
        const float4* eg4 = (const float4*)ep_g + trow * 32 + h * 16;
#pragma unroll
        for (int q = 0; q < 16; ++q) rA[q] = eg4[q];
    }

    // rB: ep[32*wid + tt][j0..j0+1]  (32 float2 = 64 VGPRs)
    float2 rB[32];
#pragma unroll
    for (int tt = 0; tt < 32; ++tt)
        rB[tt] = *(const float2*)(ep_g + (wid * 32 + tt) * NY + j0);

    const float yh0 = yhat_g[blk * NY + j0];
    const float yh1 = yhat_g[blk * NY + j0 + 1];

    // z pair in registers (each wave holds a full redundant copy across lanes)
    float z0 = 1.0f / 128.0f, z1 = 1.0f / 128.0f;
    float act0 = 1.f, act1 = 1.f;       // Michelot warm-start support indicators

    const float delta = d_delta[0];
    const float gamma = d_gamma[0];
    float c = 0.f, eta = 0.f, lam = 0.1f;

    const int zlb = h << 5;             // z lane base for this wave's column half

    for (int k = 0; k < NITER; ++k) {
        const float lr = 0.05f * __builtin_amdgcn_rsqf(1.0f + (float)k);

        // ---- phase A: half-dot ep[trow][64h:64h+64] . z[64h:64h+64] ----
        float a0 = 0.f, a1 = 0.f, a2 = 0.f, a3 = 0.f;
#pragma unroll
        for (int q = 0; q < 16; ++q) {
            const float4 e = rA[q];
            const float za = rl(z0, zlb + 2 * q);
            const float zb = rl(z1, zlb + 2 * q);
            const float zc = rl(z0, zlb + 2 * q + 1);
            const float zd = rl(z1, zlb + 2 * q + 1);
            a0 = fmaf(e.x, za, a0);
            a1 = fmaf(e.y, zb, a1);
            a2 = fmaf(e.z, zc, a2);
            a3 = fmaf(e.w, zd, a3);
        }
        part_lds[trow * 2 + h] = (a0 + a1) + (a2 + a3);

        __syncthreads();   // barrier 1: part_lds visible (also protects gz_f/red_s reuse)

        // ---- combine halves for row prow; compute st/wv (2 lanes per row) ----
        const float2 pp = *(const float2*)&part_lds[prow * 2];
        const float r  = (pp.x + pp.y) - c;
        const float q2 = r * r - eta;
        const float aa = -lam;
        const float st = (q2 > aa) ? 1.0f : ((q2 == aa) ? 0.5f : 0.0f);
        const float wv = st * r;

        // ---- S1/S2 per-wave reduction (each row counted twice -> x0.5 later) ----
        float s1 = st, s2 = wv;
        wave_sum2(s1, s2);
        if (lane == 0) { red_s[wid * 2] = s1; red_s[wid * 2 + 1] = s2; }

        // ---- phase B: partial gz over this wave's 32 rows; w via readlane ----
        float p0 = 0.f, p1 = 0.f, p2 = 0.f, p3 = 0.f;
#pragma unroll
        for (int tt = 0; tt < 32; tt += 2) {
            const float wa = rl(wv, tt);
            const float wb = rl(wv, tt + 1);
            const float2 ea = rB[tt];
            const float2 eb = rB[tt + 1];
            p0 = fmaf(wa, ea.x, p0);
            p1 = fmaf(wa, ea.y, p1);
            p2 = fmaf(wb, eb.x, p2);
            p3 = fmaf(wb, eb.y, p3);
        }
        *(float2*)&gz_f[wid * 130 + j0] = make_float2(p0 + p2, p1 + p3);

        __syncthreads();   // barrier 2: gz_f + red_s visible (also protects part_lds reuse)

        // ---- all threads redundantly: scalar updates + z step + projection ----
        const float4 rd0 = *(const float4*)&red_s[0];
        const float4 rd1 = *(const float4*)&red_s[4];
        const float4 rd2 = *(const float4*)&red_s[8];
        const float4 rd3 = *(const float4*)&red_s[12];
        const float S1 = 0.5f * (((rd0.x + rd0.z) + (rd1.x + rd1.z)) +
                                 ((rd2.x + rd2.z) + (rd3.x + rd3.z)));
        const float S2 = 0.5f * (((rd0.y + rd0.w) + (rd1.y + rd1.w)) +
                                 ((rd2.y + rd2.w) + (rd3.y + rd3.w)));
        c   -= lr * (-(2.0f / 256.0f) * S2);
        eta -= lr * (1.0f - S1 * (1.0f / 256.0f));
        lam  = fmaxf(lam - lr * (delta - 1.0f + S1 * (1.0f / 256.0f)), 0.0f);

        float g0 = 0.f, g1 = 0.f;
#pragma unroll
        for (int w = 0; w < 8; ++w) {
            const float2 gw = *(const float2*)&gz_f[w * 130 + j0];
            g0 += gw.x;
            g1 += gw.y;
        }
        const float v0 = z0 - lr * ((2.0f / 256.0f) * g0 - gamma * yh0);
        const float v1 = z1 - lr * ((2.0f / 256.0f) * g1 - gamma * yh1);

        // ---- Michelot projection: warm start + ballot fixed-point test.
        float theta = 0.f;
        for (int attempt = 0; attempt < 2; ++attempt) {
            for (int it = 0; it < 128; ++it) {
                float s  = act0 * v0 + act1 * v1;
                float cc = act0 + act1;
                wave_sum2(s, cc);
                theta = (s - 1.0f) * __builtin_amdgcn_rcpf(cc);
                const float n0 = (v0 > theta) ? act0 : 0.f;
                const float n1 = (v1 > theta) ? act1 : 0.f;
                const bool changed = (n0 != act0) || (n1 != act1);
                act0 = n0; act1 = n1;
                if (!__any(changed)) break;   // uniform
            }
            const bool viol = ((act0 == 0.f) && (v0 > theta)) ||
                              ((act1 == 0.f) && (v1 > theta));
            if (!__any(viol)) break;          // exact
            act0 = 1.f; act1 = 1.f;           // rare: support grew, restart full
        }
        z0 = fmaxf(v0 - theta, 0.f);
        z1 = fmaxf(v1 - theta, 0.f);
    }

    if (wid == 0) *(float2*)&z_out[blk * NY + j0] = make_float2(z0, z1);
}

extern "C" void kernel_launch(void* const* d_in, const int* in_sizes, int n_in,
                              void* d_out, int out_size, void* d_ws, size_t ws_size,
                              hipStream_t stream) {
    const float* X       = (const float*)d_in[0];   // 256*64
    const float* Y       = (const float*)d_in[1];   // 256*128
    const float* W       = (const float*)d_in[2];   // 128*64
    const float* b       = (const float*)d_in[3];   // 128
    const float* d_delta = (const float*)d_in[4];   // 1
    const float* d_gamma = (const float*)d_in[5];   // 1

    float* z_out    = (float*)d_out;                // Z_star: 256*128
    float* yhat_out = z_out + T_OBS * NY;           // Y_hat:  256*128
    float* ep_ws    = (float*)d_ws;                 // 256*128 scratch

    pred_kernel<<<T_OBS, 128, 0, stream>>>(X, Y, W, b, yhat_out, ep_ws);
    dro_kernel<<<T_OBS, 512, 0, stream>>>(ep_ws, yhat_out, z_out, d_delta, d_gamma);
}

// Round 3
// 288.587 us; speedup vs baseline: 1.0965x; 1.0965x over previous
//
#include <hip/hip_runtime.h>
#include <math.h>

#define T_OBS 256
#define NY 128
#define NITER 150

typedef float f2 __attribute__((ext_vector_type(2)));

// ---- gfx9/CDNA DPP wave64 reduction: row_shr 1,2,4,8 + bcast15 + bcast31 ----
#define DPP_ROW_SHR1 0x111
#define DPP_ROW_SHR2 0x112
#define DPP_ROW_SHR4 0x114
#define DPP_ROW_SHR8 0x118
#define DPP_BCAST15  0x142
#define DPP_BCAST31  0x143

#define DPP_ADD_F32(x, ctrl) \
    (x) += __int_as_float(__builtin_amdgcn_update_dpp(0, __float_as_int(x), (ctrl), 0xf, 0xf, true))

// Interleaved dual wave-sum; returns uniform totals in a,b.
__device__ __forceinline__ void wave_sum2(float& a, float& b) {
    DPP_ADD_F32(a, DPP_ROW_SHR1); DPP_ADD_F32(b, DPP_ROW_SHR1);
    DPP_ADD_F32(a, DPP_ROW_SHR2); DPP_ADD_F32(b, DPP_ROW_SHR2);
    DPP_ADD_F32(a, DPP_ROW_SHR4); DPP_ADD_F32(b, DPP_ROW_SHR4);
    DPP_ADD_F32(a, DPP_ROW_SHR8); DPP_ADD_F32(b, DPP_ROW_SHR8);
    DPP_ADD_F32(a, DPP_BCAST15);  DPP_ADD_F32(b, DPP_BCAST15);
    DPP_ADD_F32(a, DPP_BCAST31);  DPP_ADD_F32(b, DPP_BCAST31);
    a = __int_as_float(__builtin_amdgcn_readlane(__float_as_int(a), 63));
    b = __int_as_float(__builtin_amdgcn_readlane(__float_as_int(b), 63));
}

// Packed fp32 FMA: acc.lo += a.lo*b.lo ; acc.hi += a.hi*b.hi  (1 VALU instr)
__device__ __forceinline__ void pk_fma(f2& acc, f2 a, f2 b) {
    asm("v_pk_fma_f32 %0, %1, %2, %0" : "+v"(acc) : "v"(a), "v"(b));
}

// ---------------- kernel 1: Y_hat = X @ W^T + b ; ep = Y - Y_hat ----------------
__global__ __launch_bounds__(128)
void pred_kernel(const float* __restrict__ X, const float* __restrict__ Y,
                 const float* __restrict__ W, const float* __restrict__ b,
                 float* __restrict__ yhat, float* __restrict__ ep) {
    __shared__ float xrow[64];
    const int t = blockIdx.x;
    const int j = threadIdx.x;
    if (j < 64) xrow[j] = X[t * 64 + j];
    __syncthreads();
    const float* wr = W + j * 64;
    float acc = 0.f;
#pragma unroll
    for (int x = 0; x < 64; ++x) acc = fmaf(xrow[x], wr[x], acc);
    const float yh = acc + b[j];
    yhat[t * NY + j] = yh;
    ep[t * NY + j] = Y[t * NY + j] - yh;
}

// ---------------- kernel 2: one DRO solve per block (256 thr, 4 waves) ----------------
// Broadcasts (z for phase A, w for phase B) go through WAVE-PRIVATE LDS slots read
// with uniform-address ds_read_b128 (4 values/instr, broadcast, no bank conflicts,
// no barrier). FMAs are packed (v_pk_fma_f32). rA/rB pinned in VGPRs via keepalive.
__global__ __launch_bounds__(256, 1)
void dro_kernel(const float* __restrict__ ep_g, const float* __restrict__ yhat_g,
                float* __restrict__ z_out,
                const float* __restrict__ d_delta, const float* __restrict__ d_gamma) {
    __shared__ __align__(16) float z_lds[4][NY];   // wave-private z (col order)
    __shared__ __align__(16) float wdup[4][NY];    // wave-private duplicated w
    __shared__ __align__(16) float gzp[2][4][NY];  // cross-wave partials, dbuf
    __shared__ __align__(16) float red_s[2][8];    // cross-wave {S1,S2}, dbuf

    const int tid  = threadIdx.x;
    const int lane = tid & 63;
    const int wid  = tid >> 6;
    const int blk  = blockIdx.x;
    const int j0   = lane << 1;
    const int tbase = wid << 6;

    // row layout: thread tid holds ep[tid][0..127] as 64 f2 (128 VGPRs)
    f2 rA2[64];
    {
        const float4* eg4 = (const float4*)ep_g + tid * 32;
#pragma unroll
        for (int q = 0; q < 32; ++q) {
            const float4 t4 = eg4[q];
            f2 lo; lo.x = t4.x; lo.y = t4.y;
            f2 hi; hi.x = t4.z; hi.y = t4.w;
            rA2[2 * q] = lo; rA2[2 * q + 1] = hi;
        }
    }

    // col layout: lane holds ep[tbase+tt][j0..j0+1] (128 VGPRs)
    f2 rB[64];
#pragma unroll
    for (int tt = 0; tt < 64; ++tt)
        rB[tt] = *(const f2*)(ep_g + (tbase + tt) * NY + j0);

    // pin both tiles in registers — forbid rematerialization from global
#pragma unroll
    for (int i = 0; i < 64; ++i) asm volatile("" : "+v"(rA2[i]));
#pragma unroll
    for (int i = 0; i < 64; ++i) asm volatile("" : "+v"(rB[i]));

    const float yh0 = yhat_g[blk * NY + j0];
    const float yh1 = yhat_g[blk * NY + j0 + 1];

    float z0 = 1.0f / 128.0f, z1 = 1.0f / 128.0f;
    float act0 = 1.f, act1 = 1.f;     // Michelot warm-start support indicators

    const float delta = d_delta[0];
    const float gamma = d_gamma[0];
    float c = 0.f, eta = 0.f, lam = 0.1f;
    int buf = 0;

    // seed wave-private z slot
    { f2 zi; zi.x = z0; zi.y = z1; *(f2*)&z_lds[wid][j0] = zi; }

    for (int k = 0; k < NITER; ++k) {
        const float lr = 0.05f * __builtin_amdgcn_rsqf(1.0f + (float)k);

        // ---- phase A: r_t = ep[t,:].z - c ; z via uniform LDS broadcast ----
        f2 accA; accA.x = 0.f; accA.y = 0.f;
        f2 accB; accB.x = 0.f; accB.y = 0.f;
        {
            const float4* zl = (const float4*)&z_lds[wid][0];
#pragma unroll
            for (int q = 0; q < 32; ++q) {
                const float4 z4 = zl[q];
                f2 zlo; zlo.x = z4.x; zlo.y = z4.y;
                f2 zhi; zhi.x = z4.z; zhi.y = z4.w;
                pk_fma(accA, rA2[2 * q], zlo);
                pk_fma(accB, rA2[2 * q + 1], zhi);
            }
        }
        const float r  = (accA.x + accA.y) + (accB.x + accB.y) - c;
        const float q2 = r * r - eta;
        const float aa = -lam;
        const float st = (q2 > aa) ? 1.0f : ((q2 == aa) ? 0.5f : 0.0f);
        const float wv = st * r;

        // ---- S1/S2 reduction ----
        float s1 = st, s2 = wv;
        wave_sum2(s1, s2);
        if (lane == 0) { red_s[buf][wid * 2] = s1; red_s[buf][wid * 2 + 1] = s2; }

        // ---- phase B: per-wave partial gz over own 64 rows; w via LDS dup ----
        { f2 wd; wd.x = wv; wd.y = wv; *(f2*)&wdup[wid][j0] = wd; }
        f2 pP; pP.x = 0.f; pP.y = 0.f;
        f2 pQ; pQ.x = 0.f; pQ.y = 0.f;
        {
            const float4* wl = (const float4*)&wdup[wid][0];
#pragma unroll
            for (int tt = 0; tt < 64; tt += 2) {
                const float4 w4 = wl[tt >> 1];
                f2 wa; wa.x = w4.x; wa.y = w4.y;   // (w_tt,  w_tt)
                f2 wb; wb.x = w4.z; wb.y = w4.w;   // (w_tt+1,w_tt+1)
                pk_fma(pP, rB[tt], wa);
                pk_fma(pQ, rB[tt + 1], wb);
            }
        }
        { f2 gp; gp.x = pP.x + pQ.x; gp.y = pP.y + pQ.y; *(f2*)&gzp[buf][wid][j0] = gp; }

        __syncthreads();   // the ONE barrier: gzp[buf] + red_s[buf] visible

        // ---- all waves redundantly: scalar updates + z step + projection ----
        const float4 rd0 = *(const float4*)&red_s[buf][0];
        const float4 rd1 = *(const float4*)&red_s[buf][4];
        const float S1 = (rd0.x + rd0.z) + (rd1.x + rd1.z);
        const float S2 = (rd0.y + rd0.w) + (rd1.y + rd1.w);
        c   -= lr * (-(2.0f / 256.0f) * S2);
        eta -= lr * (1.0f - S1 * (1.0f / 256.0f));
        lam  = fmaxf(lam - lr * (delta - 1.0f + S1 * (1.0f / 256.0f)), 0.0f);

        const f2 g0v = *(const f2*)&gzp[buf][0][j0];
        const f2 g1v = *(const f2*)&gzp[buf][1][j0];
        const f2 g2v = *(const f2*)&gzp[buf][2][j0];
        const f2 g3v = *(const f2*)&gzp[buf][3][j0];
        const float g0 = (g0v.x + g1v.x) + (g2v.x + g3v.x);
        const float g1 = (g0v.y + g1v.y) + (g2v.y + g3v.y);
        const float v0 = z0 - lr * ((2.0f / 256.0f) * g0 - gamma * yh0);
        const float v1 = z1 - lr * ((2.0f / 256.0f) * g1 - gamma * yh1);

        // ---- Michelot projection: warm start + ballot fixed-point test ----
        float theta = 0.f;
        for (int attempt = 0; attempt < 2; ++attempt) {
            for (int m = 0; m < 128; ++m) {
                float s  = act0 * v0 + act1 * v1;
                float cc = act0 + act1;
                wave_sum2(s, cc);
                theta = (s - 1.0f) * __builtin_amdgcn_rcpf(cc);
                const float n0 = (v0 > theta) ? act0 : 0.f;
                const float n1 = (v1 > theta) ? act1 : 0.f;
                const bool changed = (n0 != act0) || (n1 != act1);
                act0 = n0; act1 = n1;
                if (!__any(changed)) break;   // uniform
            }
            const bool viol = ((act0 == 0.f) && (v0 > theta)) ||
                              ((act1 == 0.f) && (v1 > theta));
            if (!__any(viol)) break;          // exact
            act0 = 1.f; act1 = 1.f;           // rare: support grew, restart full
        }
        z0 = fmaxf(v0 - theta, 0.f);
        z1 = fmaxf(v1 - theta, 0.f);

        // publish z to wave-private slot for next iter's phase A
        { f2 zn; zn.x = z0; zn.y = z1; *(f2*)&z_lds[wid][j0] = zn; }

        buf ^= 1;
    }

    if (wid == 0) { f2 zo; zo.x = z0; zo.y = z1; *(f2*)&z_out[blk * NY + j0] = zo; }
}

extern "C" void kernel_launch(void* const* d_in, const int* in_sizes, int n_in,
                              void* d_out, int out_size, void* d_ws, size_t ws_size,
                              hipStream_t stream) {
    const float* X       = (const float*)d_in[0];   // 256*64
    const float* Y       = (const float*)d_in[1];   // 256*128
    const float* W       = (const float*)d_in[2];   // 128*64
    const float* b       = (const float*)d_in[3];   // 128
    const float* d_delta = (const float*)d_in[4];   // 1
    const float* d_gamma = (const float*)d_in[5];   // 1

    float* z_out    = (float*)d_out;                // Z_star: 256*128
    float* yhat_out = z_out + T_OBS * NY;           // Y_hat:  256*128
    float* ep_ws    = (float*)d_ws;                 // 256*128 scratch

    pred_kernel<<<T_OBS, 128, 0, stream>>>(X, Y, W, b, yhat_out, ep_ws);
    dro_kernel<<<T_OBS, 256, 0, stream>>>(ep_ws, yhat_out, z_out, d_delta, d_gamma);
}